// Round 3
// baseline (1490.888 us; speedup 1.0000x reference)
//
#include <hip/hip_runtime.h>
#include <hip/hip_bf16.h>

// GIN layer: out = relu(((1+eps)*x + segment_sum(x[src], dst)) @ W1 + b1) @ W2 + b2
// Via linearity: y = bf16(x@W1); h = relu((1+eps)*y[i] + sum_j y[j] + b1); out = h@W2 + b2.
// Aggregation: coarse bucket sort (782 buckets x 64 dst nodes) into packed (dl,src) pairs,
// then one block per bucket accumulates rows into a 64x128 f32 LDS accumulator (ds_add_f32).
// This kills the fine-CSR scattered-4B-write k_place that dominated earlier rounds.
// N=50000 nodes, E=1.6M edges, D=128.

#define N_NODES 50000
#define N_EDGES 1600000
#define D 128

#define NB_H 256                 // edge chunks (one hist block each)
#define CHUNK (N_EDGES / NB_H)   // 6250 edges; per-(chunk,bucket) rank < 6250 < 65536
#define BSH 6                    // bucket = 64 dst nodes
#define BSZ 64
#define KB 782                   // ceil(50000/64)
#define LDSW 130                 // padded accumulator row (floats) to spread DS banks

typedef __attribute__((ext_vector_type(8))) short short8;
typedef __attribute__((ext_vector_type(4))) float float4v;

__device__ inline unsigned short f2b(float f) {
    unsigned u = __builtin_bit_cast(unsigned, f);
    u = u + 0x7fffu + ((u >> 16) & 1u);  // RNE
    return (unsigned short)(u >> 16);
}
__device__ inline float b2f_lo(unsigned u) { return __builtin_bit_cast(float, u << 16); }
__device__ inline float b2f_hi(unsigned u) { return __builtin_bit_cast(float, u & 0xffff0000u); }

#define LPAD 136

// ---------------- y = bf16(x @ W1)  (f32 A staged+converted in LDS; no bias/relu) ------
// Also: block 0 detects int64-vs-int32 edge layout.
__global__ __launch_bounds__(256, 2) void k_gemmY(const float* __restrict__ x,
                                                  const float* __restrict__ Wg,
                                                  unsigned short* __restrict__ y,
                                                  const int* __restrict__ ei,
                                                  int* __restrict__ flag) {
    if (blockIdx.x == 0) {
        __shared__ int nz;
        if (threadIdx.x == 0) nz = 0;
        __syncthreads();
        if (ei[threadIdx.x * 2 + 1] != 0) atomicAdd(&nz, 1);
        __syncthreads();
        if (threadIdx.x == 0) *flag = (nz == 0) ? 1 : 0;  // 1 => int64 layout
    }

    __shared__ short Al[128 * LPAD];   // [row][k] bf16
    __shared__ short Wt[128 * LPAD];   // [n][k]   bf16 (transposed W)
    int t = threadIdx.x;
    int row0 = blockIdx.x * 128;

    const float4* X4 = (const float4*)x;
    #pragma unroll
    for (int i = 0; i < 16; ++i) {
        int idx = i * 256 + t;      // 0..4095
        int r = idx >> 5;           // 0..127
        int c = idx & 31;           // float4 within row
        float4 v = make_float4(0.f, 0.f, 0.f, 0.f);
        if (row0 + r < N_NODES) v = X4[(size_t)(row0 + r) * 32 + c];
        short4 o;
        o.x = (short)f2b(v.x); o.y = (short)f2b(v.y);
        o.z = (short)f2b(v.z); o.w = (short)f2b(v.w);
        *(short4*)&Al[r * LPAD + c * 4] = o;
    }
    const float4* W4 = (const float4*)Wg;
    #pragma unroll
    for (int i = 0; i < 16; ++i) {
        int idx = i * 256 + t;
        int k = idx >> 5;
        int n4 = idx & 31;
        float4 v = W4[k * 32 + n4];
        Wt[(n4 * 4 + 0) * LPAD + k] = (short)f2b(v.x);
        Wt[(n4 * 4 + 1) * LPAD + k] = (short)f2b(v.y);
        Wt[(n4 * 4 + 2) * LPAD + k] = (short)f2b(v.z);
        Wt[(n4 * 4 + 3) * LPAD + k] = (short)f2b(v.w);
    }
    __syncthreads();

    int wave = t >> 6;
    int lane = t & 63;
    int quad = lane >> 4;
    int l16 = lane & 15;
    int rowbase = wave * 32;

    float4v acc[2][8];
    #pragma unroll
    for (int mt = 0; mt < 2; ++mt)
        #pragma unroll
        for (int nt = 0; nt < 8; ++nt)
            acc[mt][nt] = (float4v){0.f, 0.f, 0.f, 0.f};

    #pragma unroll
    for (int kc = 0; kc < 4; ++kc) {
        int koff = kc * 32 + quad * 8;
        short8 a0 = *(const short8*)&Al[(rowbase + l16) * LPAD + koff];
        short8 a1 = *(const short8*)&Al[(rowbase + 16 + l16) * LPAD + koff];
        #pragma unroll
        for (int nt = 0; nt < 8; ++nt) {
            short8 bfr = *(const short8*)&Wt[(nt * 16 + l16) * LPAD + koff];
            acc[0][nt] = __builtin_amdgcn_mfma_f32_16x16x32_bf16(a0, bfr, acc[0][nt], 0, 0, 0);
            acc[1][nt] = __builtin_amdgcn_mfma_f32_16x16x32_bf16(a1, bfr, acc[1][nt], 0, 0, 0);
        }
    }

    #pragma unroll
    for (int mt = 0; mt < 2; ++mt) {
        int rloc = rowbase + mt * 16 + quad * 4;
        #pragma unroll
        for (int nt = 0; nt < 8; ++nt) {
            int col = nt * 16 + l16;
            #pragma unroll
            for (int r = 0; r < 4; ++r) {
                int grow = row0 + rloc + r;
                if (grow < N_NODES)
                    y[(size_t)grow * 128 + col] = f2b(acc[mt][nt][r]);
            }
        }
    }
}

// ---------------- coarse hist: 782 LDS counters per chunk; per-edge rank --------------
__global__ __launch_bounds__(1024) void k_hist(const int* __restrict__ ei,
                                               const int* __restrict__ flag,
                                               unsigned* __restrict__ cnt,
                                               unsigned short* __restrict__ rank16) {
    __shared__ unsigned hist[KB];
    int b = blockIdx.x;
    for (int i = threadIdx.x; i < KB; i += 1024) hist[i] = 0u;
    __syncthreads();
    int wide = *flag;
    int e0 = b * CHUNK;
    for (int i = threadIdx.x; i < CHUNK; i += 1024) {
        int e = e0 + i;
        long long di = (long long)N_EDGES + e;
        int d = wide ? ei[di * 2] : ei[di];
        unsigned r = 0;
        if ((unsigned)d < (unsigned)N_NODES)
            r = atomicAdd(&hist[d >> BSH], 1u);
        rank16[e] = (unsigned short)r;   // coalesced
    }
    __syncthreads();
    for (int i = threadIdx.x; i < KB; i += 1024) cnt[(size_t)b * KB + i] = hist[i];
}

// ---------------- scan A: per-bucket exclusive scan over the 256 chunks (in place) ----
// One wave per bucket. cnt[b][k] -> exclusive prefix over b; btot[k] = bucket total.
__global__ __launch_bounds__(64) void k_scanA(unsigned* __restrict__ cnt,
                                              unsigned* __restrict__ btot) {
    int k = blockIdx.x;
    int l = threadIdx.x;
    unsigned v0 = cnt[(size_t)(4 * l + 0) * KB + k];
    unsigned v1 = cnt[(size_t)(4 * l + 1) * KB + k];
    unsigned v2 = cnt[(size_t)(4 * l + 2) * KB + k];
    unsigned v3 = cnt[(size_t)(4 * l + 3) * KB + k];
    unsigned lsum = v0 + v1 + v2 + v3;
    unsigned x = lsum;
    for (int off = 1; off < 64; off <<= 1) {
        unsigned u = __shfl_up(x, off, 64);
        if (l >= off) x += u;
    }
    unsigned run = x - lsum;   // exclusive prefix of this lane's 4 chunks
    cnt[(size_t)(4 * l + 0) * KB + k] = run; run += v0;
    cnt[(size_t)(4 * l + 1) * KB + k] = run; run += v1;
    cnt[(size_t)(4 * l + 2) * KB + k] = run; run += v2;
    cnt[(size_t)(4 * l + 3) * KB + k] = run; run += v3;
    if (l == 63) btot[k] = run;
}

// ---------------- scan B: exclusive scan of 782 bucket totals -------------------------
__global__ __launch_bounds__(1024) void k_scanB(const unsigned* __restrict__ btot,
                                                unsigned* __restrict__ base) {
    __shared__ unsigned tmp[1024];
    int t = threadIdx.x;
    unsigned v = (t < KB) ? btot[t] : 0u;
    tmp[t] = v;
    __syncthreads();
    for (int off = 1; off < 1024; off <<= 1) {
        unsigned u = (t >= off) ? tmp[t - off] : 0u;
        __syncthreads();
        tmp[t] += u;
        __syncthreads();
    }
    if (t < KB) base[t] = tmp[t] - v;
}

// ---------------- place: pairs[pos] = (dl<<17)|src, runs of ~8 consecutive slots ------
__global__ __launch_bounds__(1024) void k_place(const int* __restrict__ ei,
                                                const int* __restrict__ flag,
                                                const unsigned* __restrict__ cnt,
                                                const unsigned* __restrict__ base,
                                                const unsigned short* __restrict__ rank16,
                                                unsigned* __restrict__ pairs) {
    int e = blockIdx.x * 1024 + threadIdx.x;
    if (e >= N_EDGES) return;
    int wide = *flag;
    int s = wide ? ei[(long long)e * 2] : ei[e];
    long long di = (long long)N_EDGES + e;
    int d = wide ? ei[di * 2] : ei[di];
    if ((unsigned)d < (unsigned)N_NODES) {
        int b = e / CHUNK;
        int k = d >> BSH;
        unsigned pos = base[k] + cnt[(size_t)b * KB + k] + rank16[e];
        unsigned sv = ((unsigned)s < (unsigned)N_NODES) ? (unsigned)s : 0u;
        pairs[pos] = sv | ((unsigned)(d & (BSZ - 1)) << 17);
    }
}

// ---------------- agg: one block per bucket; 64x128 f32 LDS accumulator ---------------
// h[i] = bf16(relu((1+eps)*y[i] + sum_j y[j] + b1)). Reads its pairs segment with
// 16 row-loads in flight (2 groups x unroll 8), ds_add_f32 into LDS, fused epilogue.
__global__ __launch_bounds__(512) void k_agg(const unsigned short* __restrict__ y,
                                             const unsigned* __restrict__ pairs,
                                             const unsigned* __restrict__ base,
                                             const unsigned* __restrict__ btot,
                                             const float* __restrict__ b1,
                                             unsigned short* __restrict__ h) {
    __shared__ float acc[BSZ * LDSW];   // 64 x 130 f32 = 33.3 KB
    int k = blockIdx.x;
    int t = threadIdx.x;
    for (int i = t; i < BSZ * LDSW; i += 512) acc[i] = 0.f;
    __syncthreads();

    int beg = (int)base[k];
    int tot = (int)btot[k];
    int w = t >> 6;        // wave 0..7
    int lane = t & 63;
    int g = lane >> 5;     // pair group 0..1
    int u = lane & 31;     // uint2 index within row (32 x 8 B = 256 B)
    int per = (tot + 7) >> 3;
    int wbeg = beg + w * per;
    int wend = min(wbeg + per, beg + tot);
    const uint2* yr = (const uint2*)y;

    int j = wbeg + g;
    for (; j + 14 < wend; j += 16) {
        unsigned pv[8];
        #pragma unroll
        for (int q = 0; q < 8; ++q) pv[q] = pairs[j + 2 * q];
        #pragma unroll
        for (int q = 0; q < 8; ++q) {
            unsigned src = pv[q] & 0x1FFFFu;
            unsigned dl  = pv[q] >> 17;
            uint2 A = yr[(size_t)src * 32 + u];
            float* ap = &acc[dl * LDSW + u * 4];
            atomicAdd(ap + 0, b2f_lo(A.x));
            atomicAdd(ap + 1, b2f_hi(A.x));
            atomicAdd(ap + 2, b2f_lo(A.y));
            atomicAdd(ap + 3, b2f_hi(A.y));
        }
    }
    for (; j < wend; j += 2) {
        unsigned v = pairs[j];
        unsigned src = v & 0x1FFFFu;
        unsigned dl  = v >> 17;
        uint2 A = yr[(size_t)src * 32 + u];
        float* ap = &acc[dl * LDSW + u * 4];
        atomicAdd(ap + 0, b2f_lo(A.x));
        atomicAdd(ap + 1, b2f_hi(A.x));
        atomicAdd(ap + 2, b2f_lo(A.y));
        atomicAdd(ap + 3, b2f_hi(A.y));
    }
    __syncthreads();

    // epilogue: 64 nodes x 32 uint2 = 2048 items over 512 threads
    int node0 = k << BSH;
    #pragma unroll
    for (int i = 0; i < 4; ++i) {
        int idx = i * 512 + t;
        int r  = idx >> 5;
        int cu = idx & 31;
        int node = node0 + r;
        if (node < N_NODES) {
            uint2 S = yr[(size_t)node * 32 + cu];
            float4 bv = ((const float4*)b1)[cu];
            const float* ap = &acc[r * LDSW + cu * 4];
            float f0 = fmaf(1.001f, b2f_lo(S.x), ap[0]) + bv.x;
            float f1 = fmaf(1.001f, b2f_hi(S.x), ap[1]) + bv.y;
            float f2 = fmaf(1.001f, b2f_lo(S.y), ap[2]) + bv.z;
            float f3 = fmaf(1.001f, b2f_hi(S.y), ap[3]) + bv.w;
            f0 = fmaxf(f0, 0.f); f1 = fmaxf(f1, 0.f);
            f2 = fmaxf(f2, 0.f); f3 = fmaxf(f3, 0.f);
            uint2 o;
            o.x = (unsigned)f2b(f0) | ((unsigned)f2b(f1) << 16);
            o.y = (unsigned)f2b(f2) | ((unsigned)f2b(f3) << 16);
            ((uint2*)h)[(size_t)node * 32 + cu] = o;
        }
    }
}

// ---------------- bf16 MFMA GEMM: out[M,128] = A_bf16[M,128] @ W[128,128] + b ---------
template <int RELU, int OUT_BF16>
__global__ __launch_bounds__(256, 2) void k_gemm(const unsigned short* __restrict__ A,
                                                 const float* __restrict__ Wg,
                                                 const float* __restrict__ bias,
                                                 void* __restrict__ outv, int M) {
    __shared__ short Al[128 * LPAD];   // [row][k]
    __shared__ short Wt[128 * LPAD];   // [n][k]  (transposed W)
    __shared__ float bl[128];

    int t = threadIdx.x;
    int row0 = blockIdx.x * 128;

    const uint4* A16 = (const uint4*)A;
    #pragma unroll
    for (int i = 0; i < 8; ++i) {
        int idx = i * 256 + t;      // 0..2047
        int r = idx >> 4;           // 0..127
        int c = idx & 15;           // uint4 within row
        uint4 v = make_uint4(0u, 0u, 0u, 0u);
        if (row0 + r < M) v = A16[(size_t)(row0 + r) * 16 + c];
        *(uint4*)&Al[r * LPAD + c * 8] = v;
    }
    const float4* W4 = (const float4*)Wg;
    #pragma unroll
    for (int i = 0; i < 16; ++i) {
        int idx = i * 256 + t;
        int k = idx >> 5;
        int n4 = idx & 31;
        float4 v = W4[k * 32 + n4];
        Wt[(n4 * 4 + 0) * LPAD + k] = (short)f2b(v.x);
        Wt[(n4 * 4 + 1) * LPAD + k] = (short)f2b(v.y);
        Wt[(n4 * 4 + 2) * LPAD + k] = (short)f2b(v.z);
        Wt[(n4 * 4 + 3) * LPAD + k] = (short)f2b(v.w);
    }
    if (t < 32) ((float4*)bl)[t] = ((const float4*)bias)[t];
    __syncthreads();

    int wave = t >> 6;
    int lane = t & 63;
    int quad = lane >> 4;
    int l16 = lane & 15;
    int rowbase = wave * 32;

    float4v acc[2][8];
    #pragma unroll
    for (int mt = 0; mt < 2; ++mt)
        #pragma unroll
        for (int nt = 0; nt < 8; ++nt)
            acc[mt][nt] = (float4v){0.f, 0.f, 0.f, 0.f};

    #pragma unroll
    for (int kc = 0; kc < 4; ++kc) {
        int koff = kc * 32 + quad * 8;
        short8 a0 = *(const short8*)&Al[(rowbase + l16) * LPAD + koff];
        short8 a1 = *(const short8*)&Al[(rowbase + 16 + l16) * LPAD + koff];
        #pragma unroll
        for (int nt = 0; nt < 8; ++nt) {
            short8 bfr = *(const short8*)&Wt[(nt * 16 + l16) * LPAD + koff];
            acc[0][nt] = __builtin_amdgcn_mfma_f32_16x16x32_bf16(a0, bfr, acc[0][nt], 0, 0, 0);
            acc[1][nt] = __builtin_amdgcn_mfma_f32_16x16x32_bf16(a1, bfr, acc[1][nt], 0, 0, 0);
        }
    }

    #pragma unroll
    for (int mt = 0; mt < 2; ++mt) {
        int rloc = rowbase + mt * 16 + quad * 4;
        #pragma unroll
        for (int nt = 0; nt < 8; ++nt) {
            int col = nt * 16 + l16;
            float bv = bl[col];
            #pragma unroll
            for (int r = 0; r < 4; ++r) {
                int grow = row0 + rloc + r;
                if (grow < M) {
                    float v = acc[mt][nt][r] + bv;
                    if (RELU) v = fmaxf(v, 0.f);
                    if (OUT_BF16)
                        ((unsigned short*)outv)[(size_t)grow * 128 + col] = f2b(v);
                    else
                        ((float*)outv)[(size_t)grow * 128 + col] = v;
                }
            }
        }
    }
}

extern "C" void kernel_launch(void* const* d_in, const int* in_sizes, int n_in,
                              void* d_out, int out_size, void* d_ws, size_t ws_size,
                              hipStream_t stream) {
    const float* x  = (const float*)d_in[0];
    const int*   ei = (const int*)d_in[1];
    const float* W1 = (const float*)d_in[2];
    const float* b1 = (const float*)d_in[3];
    const float* W2 = (const float*)d_in[4];
    const float* b2 = (const float*)d_in[5];
    float* out = (float*)d_out;

    // workspace layout (bytes):
    //   [0,        12.8e6)  y bf16 (x @ W1)
    //   [12.8e6,   25.6e6)  h bf16 (post-relu hidden)
    //   [25.6e6,   32.0e6)  pairs u32: (dl<<17)|src, bucket-sorted
    //   [32.0e6,   35.2e6)  rank16 u16 per edge
    //   [35.2e6,   36.1e6)  cnt/pbase u32 [256][782]
    //   [36.2e6, ...)       btot, base, flag
    char* ws = (char*)d_ws;
    unsigned short* y       = (unsigned short*)(ws);
    unsigned short* hb      = (unsigned short*)(ws + 12800000);
    unsigned*       pairs   = (unsigned*)(ws + 25600000);
    unsigned short* rank16  = (unsigned short*)(ws + 32000000);
    unsigned*       cnt     = (unsigned*)(ws + 35200000);
    unsigned*       btot    = (unsigned*)(ws + 36200000);
    unsigned*       base    = (unsigned*)(ws + 36300000);
    int*            flag    = (int*)    (ws + 36400000);

    int gblocks = (N_NODES + 127) / 128;  // 391

    k_gemmY<<<gblocks, 256, 0, stream>>>(x, W1, y, ei, flag);
    k_hist<<<NB_H, 1024, 0, stream>>>(ei, flag, cnt, rank16);
    k_scanA<<<KB, 64, 0, stream>>>(cnt, btot);
    k_scanB<<<1, 1024, 0, stream>>>(btot, base);
    k_place<<<(N_EDGES + 1023) / 1024, 1024, 0, stream>>>(ei, flag, cnt, base, rank16, pairs);
    k_agg<<<KB, 512, 0, stream>>>(y, pairs, base, btot, b1, hb);
    k_gemm<0, 0><<<gblocks, 256, 0, stream>>>(hb, W2, b2, out, N_NODES);
}

// Round 4
// 243.686 us; speedup vs baseline: 6.1181x; 6.1181x over previous
//
#include <hip/hip_runtime.h>
#include <hip/hip_bf16.h>

// GIN layer: out = relu(((1+eps)*x + segment_sum(x[src], dst)) @ W1 + b1) @ W2 + b2
// Via linearity: y = bf16(x@W1); h = relu((1+eps)*y[i] + sum_j y[j] + b1); out = h@W2 + b2.
// CSR build: per-chunk LDS-histogram counting sort (rank regenerated in k_place; no rank array).
// GEMMs: W pre-transposed to bf16 once (k_prep); staging is pure uint4/b128 copies.
// N=50000 nodes, E=1.6M edges, D=128.

#define N_NODES 50000
#define N_EDGES 1600000
#define D 128

#define NB_H 256                 // private histograms (one owner block each)
#define CHUNK (N_EDGES / NB_H)   // 6250 edges per chunk; rank max 6249 < 65536
#define HROW 50016               // ushorts per hist row (100,032 B, 128-aligned)

typedef __attribute__((ext_vector_type(8))) short short8;
typedef __attribute__((ext_vector_type(4))) float float4v;

__device__ inline unsigned short f2b(float f) {
    unsigned u = __builtin_bit_cast(unsigned, f);
    u = u + 0x7fffu + ((u >> 16) & 1u);  // RNE
    return (unsigned short)(u >> 16);
}
__device__ inline float b2f_lo(unsigned u) { return __builtin_bit_cast(float, u << 16); }
__device__ inline float b2f_hi(unsigned u) { return __builtin_bit_cast(float, u & 0xffff0000u); }

#define LPAD 136

// ---------------- prep: Wt = bf16(W^T) (compact [n][k]); edge-dtype flag --------------
__global__ __launch_bounds__(1024) void k_prep(const float* __restrict__ W1,
                                               const float* __restrict__ W2,
                                               unsigned short* __restrict__ Wt1,
                                               unsigned short* __restrict__ Wt2,
                                               const int* __restrict__ ei,
                                               int* __restrict__ flag) {
    __shared__ int nz;
    if (threadIdx.x == 0) nz = 0;
    __syncthreads();
    if (blockIdx.x == 0 && threadIdx.x < 256 && ei[threadIdx.x * 2 + 1] != 0)
        atomicAdd(&nz, 1);
    __syncthreads();
    if (blockIdx.x == 0 && threadIdx.x == 0) *flag = (nz == 0) ? 1 : 0;  // 1 => int64

    const float* W = (blockIdx.x == 0) ? W1 : W2;
    unsigned short* Wt = (blockIdx.x == 0) ? Wt1 : Wt2;
    for (int i = threadIdx.x; i < 128 * 128; i += 1024) {
        int k = i >> 7;
        int n = i & 127;           // consecutive lanes -> consecutive n: coalesced read
        Wt[n * 128 + k] = f2b(W[k * 128 + n]);
    }
}

// ---------------- MFMA GEMM: out[M,128] = A @ W + (bias) ------------------------------
// AF32: A is f32 (converted to bf16 during LDS staging), else bf16.
// Wtg: pre-transposed bf16 [n][k] compact.
template <int AF32, int BIAS, int OUT_BF16>
__global__ __launch_bounds__(256, 2) void k_mm(const void* __restrict__ Av,
                                               const unsigned short* __restrict__ Wtg,
                                               const float* __restrict__ bias,
                                               void* __restrict__ outv, int M) {
    __shared__ short Al[128 * LPAD];   // [row][k]
    __shared__ short Wt[128 * LPAD];   // [n][k]
    __shared__ float bl[128];

    int t = threadIdx.x;
    int row0 = blockIdx.x * 128;

    if (AF32) {
        const float4* X4 = (const float4*)Av;
        #pragma unroll
        for (int i = 0; i < 16; ++i) {
            int idx = i * 256 + t;      // 0..4095
            int r = idx >> 5;           // 0..127
            int c = idx & 31;           // float4 within row
            float4 v = make_float4(0.f, 0.f, 0.f, 0.f);
            if (row0 + r < M) v = X4[(size_t)(row0 + r) * 32 + c];
            short4 o;
            o.x = (short)f2b(v.x); o.y = (short)f2b(v.y);
            o.z = (short)f2b(v.z); o.w = (short)f2b(v.w);
            *(short4*)&Al[r * LPAD + c * 4] = o;
        }
    } else {
        const uint4* A16 = (const uint4*)Av;
        #pragma unroll
        for (int i = 0; i < 8; ++i) {
            int idx = i * 256 + t;      // 0..2047
            int r = idx >> 4;           // 0..127
            int c = idx & 15;           // uint4 within row
            uint4 v = make_uint4(0u, 0u, 0u, 0u);
            if (row0 + r < M) v = A16[(size_t)(row0 + r) * 16 + c];
            *(uint4*)&Al[r * LPAD + c * 8] = v;
        }
    }
    {   // Wt staging: pure vector copy, 8 uint4 per thread
        const uint4* Wg4 = (const uint4*)Wtg;
        #pragma unroll
        for (int i = 0; i < 8; ++i) {
            int idx = i * 256 + t;
            int r = idx >> 4;
            int c = idx & 15;
            *(uint4*)&Wt[r * LPAD + c * 8] = Wg4[idx];
        }
    }
    if (BIAS && t < 32) ((float4*)bl)[t] = ((const float4*)bias)[t];
    __syncthreads();

    int wave = t >> 6;
    int lane = t & 63;
    int quad = lane >> 4;
    int l16 = lane & 15;
    int rowbase = wave * 32;

    float4v acc[2][8];
    #pragma unroll
    for (int mt = 0; mt < 2; ++mt)
        #pragma unroll
        for (int nt = 0; nt < 8; ++nt)
            acc[mt][nt] = (float4v){0.f, 0.f, 0.f, 0.f};

    #pragma unroll
    for (int kc = 0; kc < 4; ++kc) {
        int koff = kc * 32 + quad * 8;
        short8 a0 = *(const short8*)&Al[(rowbase + l16) * LPAD + koff];
        short8 a1 = *(const short8*)&Al[(rowbase + 16 + l16) * LPAD + koff];
        #pragma unroll
        for (int nt = 0; nt < 8; ++nt) {
            short8 bfr = *(const short8*)&Wt[(nt * 16 + l16) * LPAD + koff];
            acc[0][nt] = __builtin_amdgcn_mfma_f32_16x16x32_bf16(a0, bfr, acc[0][nt], 0, 0, 0);
            acc[1][nt] = __builtin_amdgcn_mfma_f32_16x16x32_bf16(a1, bfr, acc[1][nt], 0, 0, 0);
        }
    }

    #pragma unroll
    for (int mt = 0; mt < 2; ++mt) {
        int rloc = rowbase + mt * 16 + quad * 4;
        #pragma unroll
        for (int nt = 0; nt < 8; ++nt) {
            int col = nt * 16 + l16;
            float bv = BIAS ? bl[col] : 0.f;
            #pragma unroll
            for (int r = 0; r < 4; ++r) {
                int grow = row0 + rloc + r;
                if (grow < M) {
                    float v = acc[mt][nt][r] + bv;
                    if (OUT_BF16)
                        ((unsigned short*)outv)[(size_t)grow * 128 + col] = f2b(v);
                    else
                        ((float*)outv)[(size_t)grow * 128 + col] = v;
                }
            }
        }
    }
}

// ---------------- LDS histogram (packed u16 pairs); counts only -----------------------
__global__ __launch_bounds__(1024) void k_hist(const int* __restrict__ ei,
                                               const int* __restrict__ flag,
                                               unsigned* __restrict__ cntw) {
    __shared__ unsigned hist[HROW / 2];  // 25008 u32 = 100,032 B
    int b = blockIdx.x;
    for (int i = threadIdx.x; i < HROW / 2; i += 1024) hist[i] = 0u;
    __syncthreads();
    int wide = *flag;
    int e0 = b * CHUNK;
    for (int i = threadIdx.x; i < CHUNK; i += 1024) {
        int e = e0 + i;
        long long di = (long long)N_EDGES + e;
        int d = wide ? ei[di * 2] : ei[di];
        if ((unsigned)d < (unsigned)N_NODES)
            atomicAdd(&hist[d >> 1], 1u << ((d & 1) * 16));
    }
    __syncthreads();
    unsigned* row = cntw + (size_t)b * (HROW / 2);
    for (int i = threadIdx.x; i < HROW / 2; i += 1024) row[i] = hist[i];
}

// ---------------- fused column scan + per-block scan of deg ---------------------------
// cnt16[b][d] -> exclusive prefix over b; deg[d] = total; offsets[d] = within-block
// exclusive prefix of deg; bsum[block] = block total.
__global__ __launch_bounds__(512) void k_colscan_scan1(unsigned short* __restrict__ cnt16,
                                                       int* __restrict__ deg,
                                                       int* __restrict__ offsets,
                                                       int* __restrict__ bsum) {
    __shared__ int tmp[512];
    int t = threadIdx.x;
    int d = blockIdx.x * 512 + t;
    int run = 0;
    if (d < N_NODES) {
        #pragma unroll 8
        for (int b = 0; b < NB_H; ++b) {
            size_t idx = (size_t)b * HROW + d;
            int v = cnt16[idx];
            cnt16[idx] = (unsigned short)run;
            run += v;
        }
        deg[d] = run;
    }
    tmp[t] = run;
    __syncthreads();
    for (int off = 1; off < 512; off <<= 1) {
        int u = (t >= off) ? tmp[t - off] : 0;
        __syncthreads();
        tmp[t] += u;
        __syncthreads();
    }
    if (d < N_NODES) offsets[d] = tmp[t] - run;
    if (t == 511) bsum[blockIdx.x] = tmp[511];
}

// ---------------- fused scan of block sums + add base ---------------------------------
__global__ __launch_bounds__(512) void k_scan23(int* __restrict__ offsets,
                                                const int* __restrict__ bsum, int nb) {
    __shared__ int tmp[128];
    int t = threadIdx.x;
    if (t < 128) tmp[t] = (t < nb) ? bsum[t] : 0;
    __syncthreads();
    for (int off = 1; off < 128; off <<= 1) {
        int v = (t >= off && t < 128) ? tmp[t - off] : 0;
        __syncthreads();
        if (t < 128) tmp[t] += v;
        __syncthreads();
    }
    int base = (blockIdx.x == 0) ? 0 : tmp[blockIdx.x - 1];
    int gid = blockIdx.x * 512 + t;
    if (gid < N_NODES) offsets[gid] += base;
}

// ---------------- place: re-histogram to regenerate rank; scatter src ids -------------
// Any per-(chunk,d) rank permutation is valid (within-dst order doesn't affect a sum),
// so ranks need not match k_hist's atomic order. No rank array round-trip.
__global__ __launch_bounds__(1024) void k_place(const int* __restrict__ ei,
                                                const int* __restrict__ flag,
                                                const int* __restrict__ offsets,
                                                const unsigned short* __restrict__ cnt16,
                                                int* __restrict__ srcs) {
    __shared__ unsigned hist[HROW / 2];
    int b = blockIdx.x;
    for (int i = threadIdx.x; i < HROW / 2; i += 1024) hist[i] = 0u;
    __syncthreads();
    int wide = *flag;
    int e0 = b * CHUNK;
    for (int i = threadIdx.x; i < CHUNK; i += 1024) {
        int e = e0 + i;
        int s = wide ? ei[(long long)e * 2] : ei[e];
        long long di = (long long)N_EDGES + e;
        int d = wide ? ei[di * 2] : ei[di];
        if ((unsigned)d < (unsigned)N_NODES) {
            int sh = (d & 1) * 16;
            unsigned old = atomicAdd(&hist[d >> 1], 1u << sh);
            int r = (old >> sh) & 0xffffu;
            if ((unsigned)s < (unsigned)N_NODES)
                srcs[offsets[d] + cnt16[(size_t)b * HROW + d] + r] = s;
        }
    }
}

// ---------------- gather over y, fused layer-1 epilogue -------------------------------
// h[i] = bf16(relu((1+eps)*y[i] + sum_{j in N(i)} y[j] + b1))
// One wave per node (block = 4 nodes). Row = 32 lanes x uint2 (256 B); 2 neighbor
// groups x unroll 8 = 16 outstanding row loads per wave.
__global__ __launch_bounds__(256) void k_gather(const unsigned short* __restrict__ y,
                                                const int* __restrict__ srcs,
                                                const int* __restrict__ offsets,
                                                const int* __restrict__ deg,
                                                const float* __restrict__ b1,
                                                unsigned short* __restrict__ h) {
    int node = blockIdx.x * 4 + (threadIdx.x >> 6);
    int lane = threadIdx.x & 63;
    int g = lane >> 5;    // neighbor group 0..1
    int u = lane & 31;    // uint2 index within row (32 x 8 B = 256 B)
    if (node >= N_NODES) return;
    int beg = offsets[node];
    int end = beg + deg[node];
    const uint2* yr = (const uint2*)y;
    float a0 = 0.f, a1 = 0.f, a2 = 0.f, a3 = 0.f;
    int j = beg + g;
    for (; j + 14 < end; j += 16) {
        int ss[8];
        #pragma unroll
        for (int q = 0; q < 8; ++q) ss[q] = srcs[j + 2 * q];
        #pragma unroll
        for (int q = 0; q < 8; ++q) {
            uint2 A = yr[(size_t)ss[q] * 32 + u];
            a0 += b2f_lo(A.x); a1 += b2f_hi(A.x);
            a2 += b2f_lo(A.y); a3 += b2f_hi(A.y);
        }
    }
    for (; j < end; j += 2) {
        uint2 A = yr[(size_t)srcs[j] * 32 + u];
        a0 += b2f_lo(A.x); a1 += b2f_hi(A.x);
        a2 += b2f_lo(A.y); a3 += b2f_hi(A.y);
    }
    a0 += __shfl_xor(a0, 32, 64); a1 += __shfl_xor(a1, 32, 64);
    a2 += __shfl_xor(a2, 32, 64); a3 += __shfl_xor(a3, 32, 64);
    if (g == 0) {
        uint2 S = yr[(size_t)node * 32 + u];           // self row (bf16 y)
        float4 bv = ((const float4*)b1)[u];            // bias cols 4u..4u+3
        float f0 = fmaf(1.001f, b2f_lo(S.x), a0) + bv.x;
        float f1 = fmaf(1.001f, b2f_hi(S.x), a1) + bv.y;
        float f2 = fmaf(1.001f, b2f_lo(S.y), a2) + bv.z;
        float f3 = fmaf(1.001f, b2f_hi(S.y), a3) + bv.w;
        f0 = fmaxf(f0, 0.f); f1 = fmaxf(f1, 0.f);
        f2 = fmaxf(f2, 0.f); f3 = fmaxf(f3, 0.f);
        uint2 o;
        o.x = (unsigned)f2b(f0) | ((unsigned)f2b(f1) << 16);
        o.y = (unsigned)f2b(f2) | ((unsigned)f2b(f3) << 16);
        ((uint2*)h)[(size_t)node * 32 + u] = o;
    }
}

extern "C" void kernel_launch(void* const* d_in, const int* in_sizes, int n_in,
                              void* d_out, int out_size, void* d_ws, size_t ws_size,
                              hipStream_t stream) {
    const float* x  = (const float*)d_in[0];
    const int*   ei = (const int*)d_in[1];
    const float* W1 = (const float*)d_in[2];
    const float* b1 = (const float*)d_in[3];
    const float* W2 = (const float*)d_in[4];
    const float* b2 = (const float*)d_in[5];
    float* out = (float*)d_out;

    // workspace layout (bytes):
    //   [0,        12.8e6)  y bf16 (x @ W1) — live gemmY .. gather
    //   [12.8e6,   38.5e6)  cnt u16 matrix (256 x 50016 x 2B) — dead after place
    //   [12.8e6,   25.6e6)  h bf16 — aliases cnt, written by gather (after place)
    //   [38.5e6,   44.9e6)  srcs
    //   [44.9e6,   45.0e6)  Wt1 bf16 [n][k]
    //   [45.0e6,   45.1e6)  Wt2 bf16 [n][k]
    //   [45.1e6, ...)       deg, offsets, bsum, flag
    char* ws = (char*)d_ws;
    unsigned short* y       = (unsigned short*)(ws);
    unsigned*       cntw    = (unsigned*)(ws + 12800000);
    unsigned short* cnt16   = (unsigned short*)(ws + 12800000);
    unsigned short* hb      = (unsigned short*)(ws + 12800000);
    int*            srcs    = (int*)  (ws + 38500000);
    unsigned short* Wt1     = (unsigned short*)(ws + 44900000);
    unsigned short* Wt2     = (unsigned short*)(ws + 45000000);
    int*            deg     = (int*)  (ws + 45100000);
    int*            offsets = (int*)  (ws + 45300000);
    int*            bsum    = (int*)  (ws + 45500000);
    int*            flag    = (int*)  (ws + 45600000);

    const int NB_SCAN = (N_NODES + 511) / 512;  // 98
    int gblocks = (N_NODES + 127) / 128;        // 391

    k_prep<<<2, 1024, 0, stream>>>(W1, W2, Wt1, Wt2, ei, flag);
    k_mm<1, 0, 1><<<gblocks, 256, 0, stream>>>(x, Wt1, nullptr, y, N_NODES);
    k_hist<<<NB_H, 1024, 0, stream>>>(ei, flag, cntw);
    k_colscan_scan1<<<NB_SCAN, 512, 0, stream>>>(cnt16, deg, offsets, bsum);
    k_scan23<<<NB_SCAN, 512, 0, stream>>>(offsets, bsum, NB_SCAN);
    k_place<<<NB_H, 1024, 0, stream>>>(ei, flag, offsets, cnt16, srcs);
    k_gather<<<(N_NODES + 3) / 4, 256, 0, stream>>>(y, srcs, offsets, deg, b1, hb);
    k_mm<0, 1, 0><<<gblocks, 256, 0, stream>>>(hb, Wt2, b2, out, N_NODES);
}

// Round 5
// 215.097 us; speedup vs baseline: 6.9312x; 1.1329x over previous
//
#include <hip/hip_runtime.h>
#include <hip/hip_bf16.h>

// GIN layer: out = relu(((1+eps)*x + segment_sum(x[src], dst)) @ W1 + b1) @ W2 + b2
// Via linearity: y = bf16(x@W1); h = relu((1+eps)*y[i] + sum_j y[j] + b1); out = h@W2 + b2.
// Edge organization: coarse bucket sort (782 buckets x 64 dst nodes) into (dl,src) pairs
// with coalesced run writes; then ONE block per bucket fine-sorts its pairs in LDS and
// gathers immediately (register sums, no DS atomics, no fine CSR, no srcs round-trip).
// N=50000 nodes, E=1.6M edges, D=128.

#define N_NODES 50000
#define N_EDGES 1600000
#define D 128

#define NB_H 256                 // edge chunks (one hist/place block each)
#define CHUNK (N_EDGES / NB_H)   // 6250 edges per chunk
#define BSH 6                    // bucket = 64 dst nodes
#define BSZ 64
#define KB 782                   // ceil(50000/64)
#define CAP 6144                 // LDS src-buffer capacity (avg bucket = 2046, 91 sigma margin)

typedef __attribute__((ext_vector_type(8))) short short8;
typedef __attribute__((ext_vector_type(4))) float float4v;

__device__ inline unsigned short f2b(float f) {
    unsigned u = __builtin_bit_cast(unsigned, f);
    u = u + 0x7fffu + ((u >> 16) & 1u);  // RNE
    return (unsigned short)(u >> 16);
}
__device__ inline float b2f_lo(unsigned u) { return __builtin_bit_cast(float, u << 16); }
__device__ inline float b2f_hi(unsigned u) { return __builtin_bit_cast(float, u & 0xffff0000u); }

#define LPAD 136

// ---------------- prep: Wt = bf16(W^T) (compact [n][k]); edge-dtype flag --------------
__global__ __launch_bounds__(1024) void k_prep(const float* __restrict__ W1,
                                               const float* __restrict__ W2,
                                               unsigned short* __restrict__ Wt1,
                                               unsigned short* __restrict__ Wt2,
                                               const int* __restrict__ ei,
                                               int* __restrict__ flag) {
    __shared__ int nz;
    if (threadIdx.x == 0) nz = 0;
    __syncthreads();
    if (blockIdx.x == 0 && threadIdx.x < 256 && ei[threadIdx.x * 2 + 1] != 0)
        atomicAdd(&nz, 1);
    __syncthreads();
    if (blockIdx.x == 0 && threadIdx.x == 0) *flag = (nz == 0) ? 1 : 0;  // 1 => int64

    const float* W = (blockIdx.x == 0) ? W1 : W2;
    unsigned short* Wt = (blockIdx.x == 0) ? Wt1 : Wt2;
    for (int i = threadIdx.x; i < 128 * 128; i += 1024) {
        int k = i >> 7;
        int n = i & 127;           // consecutive lanes -> consecutive n: coalesced read
        Wt[n * 128 + k] = f2b(W[k * 128 + n]);
    }
}

// ---------------- MFMA GEMM: out[M,128] = A @ W + (bias) ------------------------------
// AF32: A is f32 (converted to bf16 during LDS staging), else bf16.
// Wtg: pre-transposed bf16 [n][k] compact.
template <int AF32, int BIAS, int OUT_BF16>
__global__ __launch_bounds__(256, 2) void k_mm(const void* __restrict__ Av,
                                               const unsigned short* __restrict__ Wtg,
                                               const float* __restrict__ bias,
                                               void* __restrict__ outv, int M) {
    __shared__ short Al[128 * LPAD];   // [row][k]
    __shared__ short Wt[128 * LPAD];   // [n][k]
    __shared__ float bl[128];

    int t = threadIdx.x;
    int row0 = blockIdx.x * 128;

    if (AF32) {
        const float4* X4 = (const float4*)Av;
        #pragma unroll
        for (int i = 0; i < 16; ++i) {
            int idx = i * 256 + t;      // 0..4095
            int r = idx >> 5;           // 0..127
            int c = idx & 31;           // float4 within row
            float4 v = make_float4(0.f, 0.f, 0.f, 0.f);
            if (row0 + r < M) v = X4[(size_t)(row0 + r) * 32 + c];
            short4 o;
            o.x = (short)f2b(v.x); o.y = (short)f2b(v.y);
            o.z = (short)f2b(v.z); o.w = (short)f2b(v.w);
            *(short4*)&Al[r * LPAD + c * 4] = o;
        }
    } else {
        const uint4* A16 = (const uint4*)Av;
        #pragma unroll
        for (int i = 0; i < 8; ++i) {
            int idx = i * 256 + t;      // 0..2047
            int r = idx >> 4;           // 0..127
            int c = idx & 15;           // uint4 within row
            uint4 v = make_uint4(0u, 0u, 0u, 0u);
            if (row0 + r < M) v = A16[(size_t)(row0 + r) * 16 + c];
            *(uint4*)&Al[r * LPAD + c * 8] = v;
        }
    }
    {   // Wt staging: pure vector copy, 8 uint4 per thread
        const uint4* Wg4 = (const uint4*)Wtg;
        #pragma unroll
        for (int i = 0; i < 8; ++i) {
            int idx = i * 256 + t;
            int r = idx >> 4;
            int c = idx & 15;
            *(uint4*)&Wt[r * LPAD + c * 8] = Wg4[idx];
        }
    }
    if (BIAS && t < 32) ((float4*)bl)[t] = ((const float4*)bias)[t];
    __syncthreads();

    int wave = t >> 6;
    int lane = t & 63;
    int quad = lane >> 4;
    int l16 = lane & 15;
    int rowbase = wave * 32;

    float4v acc[2][8];
    #pragma unroll
    for (int mt = 0; mt < 2; ++mt)
        #pragma unroll
        for (int nt = 0; nt < 8; ++nt)
            acc[mt][nt] = (float4v){0.f, 0.f, 0.f, 0.f};

    #pragma unroll
    for (int kc = 0; kc < 4; ++kc) {
        int koff = kc * 32 + quad * 8;
        short8 a0 = *(const short8*)&Al[(rowbase + l16) * LPAD + koff];
        short8 a1 = *(const short8*)&Al[(rowbase + 16 + l16) * LPAD + koff];
        #pragma unroll
        for (int nt = 0; nt < 8; ++nt) {
            short8 bfr = *(const short8*)&Wt[(nt * 16 + l16) * LPAD + koff];
            acc[0][nt] = __builtin_amdgcn_mfma_f32_16x16x32_bf16(a0, bfr, acc[0][nt], 0, 0, 0);
            acc[1][nt] = __builtin_amdgcn_mfma_f32_16x16x32_bf16(a1, bfr, acc[1][nt], 0, 0, 0);
        }
    }

    #pragma unroll
    for (int mt = 0; mt < 2; ++mt) {
        int rloc = rowbase + mt * 16 + quad * 4;
        #pragma unroll
        for (int nt = 0; nt < 8; ++nt) {
            int col = nt * 16 + l16;
            float bv = BIAS ? bl[col] : 0.f;
            #pragma unroll
            for (int r = 0; r < 4; ++r) {
                int grow = row0 + rloc + r;
                if (grow < M) {
                    float v = acc[mt][nt][r] + bv;
                    if (OUT_BF16)
                        ((unsigned short*)outv)[(size_t)grow * 128 + col] = f2b(v);
                    else
                        ((float*)outv)[(size_t)grow * 128 + col] = v;
                }
            }
        }
    }
}

// ---------------- coarse hist: 782 LDS counters per chunk (counts only) ---------------
__global__ __launch_bounds__(1024) void k_histB(const int* __restrict__ ei,
                                                const int* __restrict__ flag,
                                                unsigned* __restrict__ cnt) {
    __shared__ unsigned hist[KB];
    int b = blockIdx.x;
    for (int i = threadIdx.x; i < KB; i += 1024) hist[i] = 0u;
    __syncthreads();
    int wide = *flag;
    int e0 = b * CHUNK;
    for (int i = threadIdx.x; i < CHUNK; i += 1024) {
        int e = e0 + i;
        long long di = (long long)N_EDGES + e;
        int d = wide ? ei[di * 2] : ei[di];
        if ((unsigned)d < (unsigned)N_NODES)
            atomicAdd(&hist[d >> BSH], 1u);
    }
    __syncthreads();
    for (int i = threadIdx.x; i < KB; i += 1024) cnt[(size_t)b * KB + i] = hist[i];
}

// ---------------- scan A: per-bucket exclusive scan over the 256 chunks (in place) ----
__global__ __launch_bounds__(64) void k_scanA(unsigned* __restrict__ cnt,
                                              unsigned* __restrict__ btot) {
    int k = blockIdx.x;
    int l = threadIdx.x;
    unsigned v0 = cnt[(size_t)(4 * l + 0) * KB + k];
    unsigned v1 = cnt[(size_t)(4 * l + 1) * KB + k];
    unsigned v2 = cnt[(size_t)(4 * l + 2) * KB + k];
    unsigned v3 = cnt[(size_t)(4 * l + 3) * KB + k];
    unsigned lsum = v0 + v1 + v2 + v3;
    unsigned x = lsum;
    for (int off = 1; off < 64; off <<= 1) {
        unsigned u = __shfl_up(x, off, 64);
        if (l >= off) x += u;
    }
    unsigned run = x - lsum;   // exclusive prefix of this lane's 4 chunks
    cnt[(size_t)(4 * l + 0) * KB + k] = run; run += v0;
    cnt[(size_t)(4 * l + 1) * KB + k] = run; run += v1;
    cnt[(size_t)(4 * l + 2) * KB + k] = run; run += v2;
    cnt[(size_t)(4 * l + 3) * KB + k] = run; run += v3;
    if (l == 63) btot[k] = run;
}

// ---------------- scan B: exclusive scan of 782 bucket totals -------------------------
__global__ __launch_bounds__(1024) void k_scanB(const unsigned* __restrict__ btot,
                                                unsigned* __restrict__ base) {
    __shared__ unsigned tmp[1024];
    int t = threadIdx.x;
    unsigned v = (t < KB) ? btot[t] : 0u;
    tmp[t] = v;
    __syncthreads();
    for (int off = 1; off < 1024; off <<= 1) {
        unsigned u = (t >= off) ? tmp[t - off] : 0u;
        __syncthreads();
        tmp[t] += u;
        __syncthreads();
    }
    if (t < KB) base[t] = tmp[t] - v;
}

// ---------------- place: re-hist to regenerate rank; pairs[pos] = (dl<<17)|src --------
// Runs of ~8 consecutive slots per (chunk,bucket) -> no write-amplification.
// Within-(chunk,bucket) order is arbitrary (sum is order-invariant).
__global__ __launch_bounds__(1024) void k_placeB(const int* __restrict__ ei,
                                                 const int* __restrict__ flag,
                                                 const unsigned* __restrict__ cnt,
                                                 const unsigned* __restrict__ base,
                                                 unsigned* __restrict__ pairs) {
    __shared__ unsigned hist[KB];
    int b = blockIdx.x;
    for (int i = threadIdx.x; i < KB; i += 1024) hist[i] = 0u;
    __syncthreads();
    int wide = *flag;
    int e0 = b * CHUNK;
    for (int i = threadIdx.x; i < CHUNK; i += 1024) {
        int e = e0 + i;
        int s = wide ? ei[(long long)e * 2] : ei[e];
        long long di = (long long)N_EDGES + e;
        int d = wide ? ei[di * 2] : ei[di];
        if ((unsigned)d < (unsigned)N_NODES) {
            int kb = d >> BSH;
            unsigned r = atomicAdd(&hist[kb], 1u);
            unsigned sv = ((unsigned)s < (unsigned)N_NODES) ? (unsigned)s : 0u;
            pairs[base[kb] + cnt[(size_t)b * KB + kb] + r] = sv | ((unsigned)(d & (BSZ - 1)) << 17);
        }
    }
}

// ---------------- bucket gather: fine sort in LDS + register-sum gather ---------------
// One block (8 waves) per bucket of 64 dst nodes. Fine-sorts its pairs into an LDS
// src buffer (count -> wave scan -> scatter), then each wave gathers 8 nodes with the
// 16-outstanding-row-loads loop; h[i] = bf16(relu((1+eps)*y[i] + sum_j y[j] + b1)).
__global__ __launch_bounds__(512) void k_bgather(const unsigned short* __restrict__ y,
                                                 const unsigned* __restrict__ pairs,
                                                 const unsigned* __restrict__ base,
                                                 const unsigned* __restrict__ btot,
                                                 const float* __restrict__ b1,
                                                 unsigned short* __restrict__ h) {
    __shared__ unsigned sbuf[CAP];           // 24,576 B
    __shared__ int cnt[BSZ], loff[BSZ], pos[BSZ];
    int k = blockIdx.x;
    int t = threadIdx.x;
    if (t < BSZ) cnt[t] = 0;
    __syncthreads();
    int beg = (int)base[k];
    int tot = (int)btot[k];
    for (int i = t; i < tot; i += 512)
        atomicAdd(&cnt[pairs[beg + i] >> 17], 1);
    __syncthreads();
    if (t < BSZ) {   // wave 0: exclusive scan of the 64 counters
        int v = cnt[t];
        int xs = v;
        #pragma unroll
        for (int off = 1; off < 64; off <<= 1) {
            int u0 = __shfl_up(xs, off, 64);
            if (t >= off) xs += u0;
        }
        loff[t] = xs - v;
        pos[t] = xs - v;
    }
    __syncthreads();
    for (int i = t; i < tot; i += 512) {
        unsigned p = pairs[beg + i];
        int r = atomicAdd(&pos[p >> 17], 1);
        if (r < CAP) sbuf[r] = p & 0x1FFFFu;
    }
    __syncthreads();

    int w = t >> 6;
    int lane = t & 63;
    int g = lane >> 5;    // neighbor group 0..1
    int u = lane & 31;    // uint2 index within row (32 x 8 B = 256 B)
    const uint2* yr = (const uint2*)y;

    #pragma unroll 1
    for (int q = 0; q < 8; ++q) {     // each wave: 8 nodes
        int dl = w * 8 + q;
        int node = (k << BSH) + dl;
        if (node >= N_NODES) break;
        int jb = loff[dl];
        int je = jb + cnt[dl];
        if (je > CAP) je = CAP;       // safety clamp (unreachable for this input)
        float a0 = 0.f, a1 = 0.f, a2 = 0.f, a3 = 0.f;
        int j = jb + g;
        for (; j + 14 < je; j += 16) {
            int ss[8];
            #pragma unroll
            for (int q2 = 0; q2 < 8; ++q2) ss[q2] = (int)sbuf[j + 2 * q2];
            #pragma unroll
            for (int q2 = 0; q2 < 8; ++q2) {
                uint2 A = yr[(size_t)ss[q2] * 32 + u];
                a0 += b2f_lo(A.x); a1 += b2f_hi(A.x);
                a2 += b2f_lo(A.y); a3 += b2f_hi(A.y);
            }
        }
        for (; j < je; j += 2) {
            uint2 A = yr[(size_t)sbuf[j] * 32 + u];
            a0 += b2f_lo(A.x); a1 += b2f_hi(A.x);
            a2 += b2f_lo(A.y); a3 += b2f_hi(A.y);
        }
        a0 += __shfl_xor(a0, 32, 64); a1 += __shfl_xor(a1, 32, 64);
        a2 += __shfl_xor(a2, 32, 64); a3 += __shfl_xor(a3, 32, 64);
        if (g == 0) {
            uint2 S = yr[(size_t)node * 32 + u];   // self row (bf16 y)
            float4 bv = ((const float4*)b1)[u];    // bias cols 4u..4u+3
            float f0 = fmaf(1.001f, b2f_lo(S.x), a0) + bv.x;
            float f1 = fmaf(1.001f, b2f_hi(S.x), a1) + bv.y;
            float f2 = fmaf(1.001f, b2f_lo(S.y), a2) + bv.z;
            float f3 = fmaf(1.001f, b2f_hi(S.y), a3) + bv.w;
            f0 = fmaxf(f0, 0.f); f1 = fmaxf(f1, 0.f);
            f2 = fmaxf(f2, 0.f); f3 = fmaxf(f3, 0.f);
            uint2 o;
            o.x = (unsigned)f2b(f0) | ((unsigned)f2b(f1) << 16);
            o.y = (unsigned)f2b(f2) | ((unsigned)f2b(f3) << 16);
            ((uint2*)h)[(size_t)node * 32 + u] = o;
        }
    }
}

extern "C" void kernel_launch(void* const* d_in, const int* in_sizes, int n_in,
                              void* d_out, int out_size, void* d_ws, size_t ws_size,
                              hipStream_t stream) {
    const float* x  = (const float*)d_in[0];
    const int*   ei = (const int*)d_in[1];
    const float* W1 = (const float*)d_in[2];
    const float* b1 = (const float*)d_in[3];
    const float* W2 = (const float*)d_in[4];
    const float* b2 = (const float*)d_in[5];
    float* out = (float*)d_out;

    // workspace layout (bytes):
    //   [0,        12.8e6)  y bf16 (x @ W1)
    //   [12.8e6,   25.6e6)  h bf16 (post-relu hidden)
    //   [25.6e6,   32.0e6)  pairs u32: (dl<<17)|src, bucket-sorted
    //   [32.0e6,   32.9e6)  cnt u32 [256][782] (scanned in place)
    //   [33.0e6,   ...)     btot, base, Wt1, Wt2, flag
    char* ws = (char*)d_ws;
    unsigned short* y       = (unsigned short*)(ws);
    unsigned short* hb      = (unsigned short*)(ws + 12800000);
    unsigned*       pairs   = (unsigned*)(ws + 25600000);
    unsigned*       cnt     = (unsigned*)(ws + 32000000);
    unsigned*       btot    = (unsigned*)(ws + 33000000);
    unsigned*       base    = (unsigned*)(ws + 33100000);
    unsigned short* Wt1     = (unsigned short*)(ws + 33200000);
    unsigned short* Wt2     = (unsigned short*)(ws + 33300000);
    int*            flag    = (int*)    (ws + 33400000);

    int gblocks = (N_NODES + 127) / 128;  // 391

    k_prep<<<2, 1024, 0, stream>>>(W1, W2, Wt1, Wt2, ei, flag);
    k_mm<1, 0, 1><<<gblocks, 256, 0, stream>>>(x, Wt1, nullptr, y, N_NODES);
    k_histB<<<NB_H, 1024, 0, stream>>>(ei, flag, cnt);
    k_scanA<<<KB, 64, 0, stream>>>(cnt, btot);
    k_scanB<<<1, 1024, 0, stream>>>(btot, base);
    k_placeB<<<NB_H, 1024, 0, stream>>>(ei, flag, cnt, base, pairs);
    k_bgather<<<KB, 512, 0, stream>>>(y, pairs, base, btot, b1, hb);
    k_mm<0, 1, 0><<<gblocks, 256, 0, stream>>>(hb, Wt2, b2, out, N_NODES);
}

// Round 6
// 196.808 us; speedup vs baseline: 7.5753x; 1.0929x over previous
//
#include <hip/hip_runtime.h>
#include <hip/hip_bf16.h>

// GIN layer: out = relu(((1+eps)*x + segment_sum(x[src], dst)) @ W1 + b1) @ W2 + b2
// Via linearity: y = bf16(x@W1); h = relu((1+eps)*y[i] + sum_j y[j] + b1); out = h@W2 + b2.
// Edge organization: single-kernel bucket sort. Each bucket (64 dst nodes) owns a FIXED
// CAPB-slot region of `pairs`; each chunk-block counts per-bucket in LDS, reserves a range
// per bucket via one global atomicAdd, then scatters (dl<<17)|src with LDS-ranked offsets.
// k_bgather fine-sorts each bucket in LDS and gathers with register sums (R5 scheme).
// N=50000 nodes, E=1.6M edges, D=128.

#define N_NODES 50000
#define N_EDGES 1600000
#define D 128

#define NB_H 256                 // edge chunks (one sort block each)
#define CHUNK (N_EDGES / NB_H)   // 6250 edges per chunk
#define EPT 7                    // ceil(CHUNK/1024) edges per thread (register-cached)
#define BSH 6                    // bucket = 64 dst nodes
#define BSZ 64
#define KB 782                   // ceil(50000/64)
#define CAPB 2560                // fixed slots per bucket (mean 2048, sd ~45 -> 11 sigma)

typedef __attribute__((ext_vector_type(8))) short short8;
typedef __attribute__((ext_vector_type(4))) float float4v;

__device__ inline unsigned short f2b(float f) {
    unsigned u = __builtin_bit_cast(unsigned, f);
    u = u + 0x7fffu + ((u >> 16) & 1u);  // RNE
    return (unsigned short)(u >> 16);
}
__device__ inline float b2f_lo(unsigned u) { return __builtin_bit_cast(float, u << 16); }
__device__ inline float b2f_hi(unsigned u) { return __builtin_bit_cast(float, u & 0xffff0000u); }

#define LPAD 136

// ---------------- prep: Wt = bf16(W^T); zero bucket cursors; edge-dtype flag ----------
__global__ __launch_bounds__(1024) void k_prep(const float* __restrict__ W1,
                                               const float* __restrict__ W2,
                                               unsigned short* __restrict__ Wt1,
                                               unsigned short* __restrict__ Wt2,
                                               unsigned* __restrict__ bpos,
                                               const int* __restrict__ ei,
                                               int* __restrict__ flag) {
    __shared__ int nz;
    if (threadIdx.x == 0) nz = 0;
    __syncthreads();
    if (blockIdx.x == 0 && threadIdx.x < 256 && ei[threadIdx.x * 2 + 1] != 0)
        atomicAdd(&nz, 1);
    __syncthreads();
    if (blockIdx.x == 0 && threadIdx.x == 0) *flag = (nz == 0) ? 1 : 0;  // 1 => int64
    if (blockIdx.x == 0)
        for (int i = threadIdx.x; i < KB; i += 1024) bpos[i] = 0u;

    const float* W = (blockIdx.x == 0) ? W1 : W2;
    unsigned short* Wt = (blockIdx.x == 0) ? Wt1 : Wt2;
    for (int i = threadIdx.x; i < 128 * 128; i += 1024) {
        int k = i >> 7;
        int n = i & 127;           // consecutive lanes -> consecutive n: coalesced read
        Wt[n * 128 + k] = f2b(W[k * 128 + n]);
    }
}

// ---------------- MFMA GEMM: out[M,128] = A @ W + (bias) ------------------------------
// AF32: A is f32 (converted to bf16 during LDS staging), else bf16.
// Wtg: pre-transposed bf16 [n][k] compact.
template <int AF32, int BIAS, int OUT_BF16>
__global__ __launch_bounds__(256, 2) void k_mm(const void* __restrict__ Av,
                                               const unsigned short* __restrict__ Wtg,
                                               const float* __restrict__ bias,
                                               void* __restrict__ outv, int M) {
    __shared__ short Al[128 * LPAD];   // [row][k]
    __shared__ short Wt[128 * LPAD];   // [n][k]
    __shared__ float bl[128];

    int t = threadIdx.x;
    int row0 = blockIdx.x * 128;

    if (AF32) {
        const float4* X4 = (const float4*)Av;
        #pragma unroll
        for (int i = 0; i < 16; ++i) {
            int idx = i * 256 + t;      // 0..4095
            int r = idx >> 5;           // 0..127
            int c = idx & 31;           // float4 within row
            float4 v = make_float4(0.f, 0.f, 0.f, 0.f);
            if (row0 + r < M) v = X4[(size_t)(row0 + r) * 32 + c];
            short4 o;
            o.x = (short)f2b(v.x); o.y = (short)f2b(v.y);
            o.z = (short)f2b(v.z); o.w = (short)f2b(v.w);
            *(short4*)&Al[r * LPAD + c * 4] = o;
        }
    } else {
        const uint4* A16 = (const uint4*)Av;
        #pragma unroll
        for (int i = 0; i < 8; ++i) {
            int idx = i * 256 + t;      // 0..2047
            int r = idx >> 4;           // 0..127
            int c = idx & 15;           // uint4 within row
            uint4 v = make_uint4(0u, 0u, 0u, 0u);
            if (row0 + r < M) v = A16[(size_t)(row0 + r) * 16 + c];
            *(uint4*)&Al[r * LPAD + c * 8] = v;
        }
    }
    {   // Wt staging: pure vector copy, 8 uint4 per thread
        const uint4* Wg4 = (const uint4*)Wtg;
        #pragma unroll
        for (int i = 0; i < 8; ++i) {
            int idx = i * 256 + t;
            int r = idx >> 4;
            int c = idx & 15;
            *(uint4*)&Wt[r * LPAD + c * 8] = Wg4[idx];
        }
    }
    if (BIAS && t < 32) ((float4*)bl)[t] = ((const float4*)bias)[t];
    __syncthreads();

    int wave = t >> 6;
    int lane = t & 63;
    int quad = lane >> 4;
    int l16 = lane & 15;
    int rowbase = wave * 32;

    float4v acc[2][8];
    #pragma unroll
    for (int mt = 0; mt < 2; ++mt)
        #pragma unroll
        for (int nt = 0; nt < 8; ++nt)
            acc[mt][nt] = (float4v){0.f, 0.f, 0.f, 0.f};

    #pragma unroll
    for (int kc = 0; kc < 4; ++kc) {
        int koff = kc * 32 + quad * 8;
        short8 a0 = *(const short8*)&Al[(rowbase + l16) * LPAD + koff];
        short8 a1 = *(const short8*)&Al[(rowbase + 16 + l16) * LPAD + koff];
        #pragma unroll
        for (int nt = 0; nt < 8; ++nt) {
            short8 bfr = *(const short8*)&Wt[(nt * 16 + l16) * LPAD + koff];
            acc[0][nt] = __builtin_amdgcn_mfma_f32_16x16x32_bf16(a0, bfr, acc[0][nt], 0, 0, 0);
            acc[1][nt] = __builtin_amdgcn_mfma_f32_16x16x32_bf16(a1, bfr, acc[1][nt], 0, 0, 0);
        }
    }

    #pragma unroll
    for (int mt = 0; mt < 2; ++mt) {
        int rloc = rowbase + mt * 16 + quad * 4;
        #pragma unroll
        for (int nt = 0; nt < 8; ++nt) {
            int col = nt * 16 + l16;
            float bv = BIAS ? bl[col] : 0.f;
            #pragma unroll
            for (int r = 0; r < 4; ++r) {
                int grow = row0 + rloc + r;
                if (grow < M) {
                    float v = acc[mt][nt][r] + bv;
                    if (OUT_BF16)
                        ((unsigned short*)outv)[(size_t)grow * 128 + col] = f2b(v);
                    else
                        ((float*)outv)[(size_t)grow * 128 + col] = v;
                }
            }
        }
    }
}

// ---------------- sort: count (LDS) -> reserve (1 global atomic per block,bucket) -----
// -> place into bucket k's fixed region [k*CAPB, (k+1)*CAPB). Edges cached in registers
// between passes; ei read exactly once. bpos[k] ends as the bucket total.
__global__ __launch_bounds__(1024) void k_sort(const int* __restrict__ ei,
                                               const int* __restrict__ flag,
                                               unsigned* __restrict__ bpos,
                                               unsigned* __restrict__ pairs) {
    __shared__ unsigned hist[KB];
    __shared__ unsigned bbase[KB];
    int b = blockIdx.x;
    int t = threadIdx.x;
    for (int i = t; i < KB; i += 1024) hist[i] = 0u;
    __syncthreads();
    int wide = *flag;
    int e0 = b * CHUNK;
    int dv[EPT], sv[EPT];
    #pragma unroll
    for (int i = 0; i < EPT; ++i) {
        dv[i] = -1; sv[i] = 0;
        int o = i * 1024 + t;
        if (o < CHUNK) {
            int e = e0 + o;
            long long di = (long long)N_EDGES + e;
            int d = wide ? ei[di * 2] : ei[di];
            int s = wide ? ei[(long long)e * 2] : ei[e];
            if ((unsigned)d < (unsigned)N_NODES) {
                dv[i] = d;
                sv[i] = ((unsigned)s < (unsigned)N_NODES) ? s : 0;
                atomicAdd(&hist[d >> BSH], 1u);
            }
        }
    }
    __syncthreads();
    for (int i = t; i < KB; i += 1024) {
        unsigned c = hist[i];
        bbase[i] = c ? atomicAdd(&bpos[i], c) : 0u;
        hist[i] = 0u;   // reuse as rank counter
    }
    __syncthreads();
    #pragma unroll
    for (int i = 0; i < EPT; ++i) {
        if (dv[i] >= 0) {
            int kb = dv[i] >> BSH;
            unsigned r = bbase[kb] + atomicAdd(&hist[kb], 1u);
            if (r < CAPB)
                pairs[(size_t)kb * CAPB + r] =
                    (unsigned)sv[i] | ((unsigned)(dv[i] & (BSZ - 1)) << 17);
        }
    }
}

// ---------------- bucket gather: fine sort in LDS + register-sum gather ---------------
// One block (8 waves) per bucket of 64 dst nodes. Fine-sorts its pairs into an LDS
// src buffer (count -> wave scan -> scatter), then each wave gathers 8 nodes with the
// 16-outstanding-row-loads loop; h[i] = bf16(relu((1+eps)*y[i] + sum_j y[j] + b1)).
__global__ __launch_bounds__(512) void k_bgather(const unsigned short* __restrict__ y,
                                                 const unsigned* __restrict__ pairs,
                                                 const unsigned* __restrict__ bpos,
                                                 const float* __restrict__ b1,
                                                 unsigned short* __restrict__ h) {
    __shared__ unsigned sbuf[CAPB];          // 10,240 B
    __shared__ int cnt[BSZ], loff[BSZ], pos[BSZ];
    int k = blockIdx.x;
    int t = threadIdx.x;
    if (t < BSZ) cnt[t] = 0;
    __syncthreads();
    int beg = k * CAPB;
    int tot = (int)bpos[k];
    if (tot > CAPB) tot = CAPB;
    for (int i = t; i < tot; i += 512)
        atomicAdd(&cnt[pairs[beg + i] >> 17], 1);
    __syncthreads();
    if (t < BSZ) {   // wave 0: exclusive scan of the 64 counters
        int v = cnt[t];
        int xs = v;
        #pragma unroll
        for (int off = 1; off < 64; off <<= 1) {
            int u0 = __shfl_up(xs, off, 64);
            if (t >= off) xs += u0;
        }
        loff[t] = xs - v;
        pos[t] = xs - v;
    }
    __syncthreads();
    for (int i = t; i < tot; i += 512) {
        unsigned p = pairs[beg + i];
        int r = atomicAdd(&pos[p >> 17], 1);
        if (r < CAPB) sbuf[r] = p & 0x1FFFFu;
    }
    __syncthreads();

    int w = t >> 6;
    int lane = t & 63;
    int g = lane >> 5;    // neighbor group 0..1
    int u = lane & 31;    // uint2 index within row (32 x 8 B = 256 B)
    const uint2* yr = (const uint2*)y;

    #pragma unroll 1
    for (int q = 0; q < 8; ++q) {     // each wave: 8 nodes
        int dl = w * 8 + q;
        int node = (k << BSH) + dl;
        if (node >= N_NODES) break;
        int jb = loff[dl];
        int je = jb + cnt[dl];
        if (je > CAPB) je = CAPB;     // safety clamp (unreachable for this input)
        float a0 = 0.f, a1 = 0.f, a2 = 0.f, a3 = 0.f;
        int j = jb + g;
        for (; j + 14 < je; j += 16) {
            int ss[8];
            #pragma unroll
            for (int q2 = 0; q2 < 8; ++q2) ss[q2] = (int)sbuf[j + 2 * q2];
            #pragma unroll
            for (int q2 = 0; q2 < 8; ++q2) {
                uint2 A = yr[(size_t)ss[q2] * 32 + u];
                a0 += b2f_lo(A.x); a1 += b2f_hi(A.x);
                a2 += b2f_lo(A.y); a3 += b2f_hi(A.y);
            }
        }
        for (; j < je; j += 2) {
            uint2 A = yr[(size_t)sbuf[j] * 32 + u];
            a0 += b2f_lo(A.x); a1 += b2f_hi(A.x);
            a2 += b2f_lo(A.y); a3 += b2f_hi(A.y);
        }
        a0 += __shfl_xor(a0, 32, 64); a1 += __shfl_xor(a1, 32, 64);
        a2 += __shfl_xor(a2, 32, 64); a3 += __shfl_xor(a3, 32, 64);
        if (g == 0) {
            uint2 S = yr[(size_t)node * 32 + u];   // self row (bf16 y)
            float4 bv = ((const float4*)b1)[u];    // bias cols 4u..4u+3
            float f0 = fmaf(1.001f, b2f_lo(S.x), a0) + bv.x;
            float f1 = fmaf(1.001f, b2f_hi(S.x), a1) + bv.y;
            float f2 = fmaf(1.001f, b2f_lo(S.y), a2) + bv.z;
            float f3 = fmaf(1.001f, b2f_hi(S.y), a3) + bv.w;
            f0 = fmaxf(f0, 0.f); f1 = fmaxf(f1, 0.f);
            f2 = fmaxf(f2, 0.f); f3 = fmaxf(f3, 0.f);
            uint2 o;
            o.x = (unsigned)f2b(f0) | ((unsigned)f2b(f1) << 16);
            o.y = (unsigned)f2b(f2) | ((unsigned)f2b(f3) << 16);
            ((uint2*)h)[(size_t)node * 32 + u] = o;
        }
    }
}

extern "C" void kernel_launch(void* const* d_in, const int* in_sizes, int n_in,
                              void* d_out, int out_size, void* d_ws, size_t ws_size,
                              hipStream_t stream) {
    const float* x  = (const float*)d_in[0];
    const int*   ei = (const int*)d_in[1];
    const float* W1 = (const float*)d_in[2];
    const float* b1 = (const float*)d_in[3];
    const float* W2 = (const float*)d_in[4];
    const float* b2 = (const float*)d_in[5];
    float* out = (float*)d_out;

    // workspace layout (bytes):
    //   [0,        12.8e6)  y bf16 (x @ W1)
    //   [12.8e6,   25.6e6)  h bf16 (post-relu hidden)
    //   [25.6e6,   33.7e6)  pairs u32: 782 buckets x 2560 slots, (dl<<17)|src
    //   [33.8e6,   ...)     bpos (782 u32), Wt1, Wt2, flag
    char* ws = (char*)d_ws;
    unsigned short* y       = (unsigned short*)(ws);
    unsigned short* hb      = (unsigned short*)(ws + 12800000);
    unsigned*       pairs   = (unsigned*)(ws + 25600000);
    unsigned*       bpos    = (unsigned*)(ws + 33800000);
    unsigned short* Wt1     = (unsigned short*)(ws + 33900000);
    unsigned short* Wt2     = (unsigned short*)(ws + 34000000);
    int*            flag    = (int*)    (ws + 34100000);

    int gblocks = (N_NODES + 127) / 128;  // 391

    k_prep<<<2, 1024, 0, stream>>>(W1, W2, Wt1, Wt2, bpos, ei, flag);
    k_mm<1, 0, 1><<<gblocks, 256, 0, stream>>>(x, Wt1, nullptr, y, N_NODES);
    k_sort<<<NB_H, 1024, 0, stream>>>(ei, flag, bpos, pairs);
    k_bgather<<<KB, 512, 0, stream>>>(y, pairs, bpos, b1, hb);
    k_mm<0, 1, 0><<<gblocks, 256, 0, stream>>>(hb, Wt2, b2, out, N_NODES);
}

// Round 7
// 194.210 us; speedup vs baseline: 7.6767x; 1.0134x over previous
//
#include <hip/hip_runtime.h>
#include <hip/hip_bf16.h>

// GIN layer: out = relu(((1+eps)*x + segment_sum(x[src], dst)) @ W1 + b1) @ W2 + b2
// Via linearity: y = bf16(x@W1); h = relu((1+eps)*y[i] + sum_j y[j] + b1); out = h@W2 + b2.
// Pipeline (4 kernels):
//   k_prep : W1,W2 -> bf16 [n][k] transposes; zero bucket cursors; edge-dtype flag
//   k_mm   : y = bf16(x @ W1)             (MFMA, f32->bf16 staged in LDS)
//   k_sort : bucket sort edges (782 buckets x 64 dst) into fixed CAPB regions; one LDS
//            rank pass (rank kept in regs), one global atomicAdd per (block,bucket)
//   k_bgather: per bucket: fine-sort pairs in LDS -> register-sum gather -> h tile in
//            LDS -> fused layer-2 MFMA (htile @ W2^T + b2) -> out f32. No h round-trip.
// N=50000 nodes, E=1.6M edges, D=128.

#define N_NODES 50000
#define N_EDGES 1600000
#define D 128

#define SB 196                   // sort blocks
#define SCH 8192                 // edges per sort block (196*8192 = 1,605,632 >= E; E%8==0)
#define BSH 6                    // bucket = 64 dst nodes
#define BSZ 64
#define KB 782                   // ceil(50000/64)
#define CAPB 2560                // fixed slots per bucket (mean 2048, sd ~45 -> 11 sigma)
#define HP 136                   // htile padded row (shorts)

typedef __attribute__((ext_vector_type(8))) short short8;
typedef __attribute__((ext_vector_type(4))) float float4v;

__device__ inline unsigned short f2b(float f) {
    unsigned u = __builtin_bit_cast(unsigned, f);
    u = u + 0x7fffu + ((u >> 16) & 1u);  // RNE
    return (unsigned short)(u >> 16);
}
__device__ inline float b2f_lo(unsigned u) { return __builtin_bit_cast(float, u << 16); }
__device__ inline float b2f_hi(unsigned u) { return __builtin_bit_cast(float, u & 0xffff0000u); }

#define LPAD 136

// ---------------- prep: Wt = bf16(W^T); zero bucket cursors; edge-dtype flag ----------
__global__ __launch_bounds__(1024) void k_prep(const float* __restrict__ W1,
                                               const float* __restrict__ W2,
                                               unsigned short* __restrict__ Wt1,
                                               unsigned short* __restrict__ Wt2,
                                               unsigned* __restrict__ bpos,
                                               const int* __restrict__ ei,
                                               int* __restrict__ flag) {
    int bb = blockIdx.x;
    if (bb == 0) {
        __shared__ int nz;
        if (threadIdx.x == 0) nz = 0;
        __syncthreads();
        if (threadIdx.x < 256 && ei[threadIdx.x * 2 + 1] != 0) atomicAdd(&nz, 1);
        __syncthreads();
        if (threadIdx.x == 0) *flag = (nz == 0) ? 1 : 0;  // 1 => int64 layout
        for (int i = threadIdx.x; i < KB; i += 1024) bpos[i] = 0u;
    }
    const float* W = (bb < 4) ? W1 : W2;
    unsigned short* Wt = (bb < 4) ? Wt1 : Wt2;
    int q = bb & 3;
    for (int i = q * 4096 + threadIdx.x; i < (q + 1) * 4096; i += 1024) {
        int k = i >> 7;
        int n = i & 127;           // consecutive lanes -> consecutive n: coalesced read
        Wt[n * 128 + k] = f2b(W[k * 128 + n]);
    }
}

// ---------------- MFMA GEMM: y[M,128] = bf16(A_f32 @ W) -------------------------------
__global__ __launch_bounds__(256, 2) void k_mm(const float* __restrict__ Av,
                                               const unsigned short* __restrict__ Wtg,
                                               unsigned short* __restrict__ y, int M) {
    __shared__ short Al[128 * LPAD];   // [row][k]
    __shared__ short Wt[128 * LPAD];   // [n][k]

    int t = threadIdx.x;
    int row0 = blockIdx.x * 128;

    const float4* X4 = (const float4*)Av;
    #pragma unroll
    for (int i = 0; i < 16; ++i) {
        int idx = i * 256 + t;      // 0..4095
        int r = idx >> 5;           // 0..127
        int c = idx & 31;           // float4 within row
        float4 v = make_float4(0.f, 0.f, 0.f, 0.f);
        if (row0 + r < M) v = X4[(size_t)(row0 + r) * 32 + c];
        short4 o;
        o.x = (short)f2b(v.x); o.y = (short)f2b(v.y);
        o.z = (short)f2b(v.z); o.w = (short)f2b(v.w);
        *(short4*)&Al[r * LPAD + c * 4] = o;
    }
    {   // Wt staging: pure vector copy, 8 uint4 per thread
        const uint4* Wg4 = (const uint4*)Wtg;
        #pragma unroll
        for (int i = 0; i < 8; ++i) {
            int idx = i * 256 + t;
            int r = idx >> 4;
            int c = idx & 15;
            *(uint4*)&Wt[r * LPAD + c * 8] = Wg4[idx];
        }
    }
    __syncthreads();

    int wave = t >> 6;
    int lane = t & 63;
    int quad = lane >> 4;
    int l16 = lane & 15;
    int rowbase = wave * 32;

    float4v acc[2][8];
    #pragma unroll
    for (int mt = 0; mt < 2; ++mt)
        #pragma unroll
        for (int nt = 0; nt < 8; ++nt)
            acc[mt][nt] = (float4v){0.f, 0.f, 0.f, 0.f};

    #pragma unroll
    for (int kc = 0; kc < 4; ++kc) {
        int koff = kc * 32 + quad * 8;
        short8 a0 = *(const short8*)&Al[(rowbase + l16) * LPAD + koff];
        short8 a1 = *(const short8*)&Al[(rowbase + 16 + l16) * LPAD + koff];
        #pragma unroll
        for (int nt = 0; nt < 8; ++nt) {
            short8 bfr = *(const short8*)&Wt[(nt * 16 + l16) * LPAD + koff];
            acc[0][nt] = __builtin_amdgcn_mfma_f32_16x16x32_bf16(a0, bfr, acc[0][nt], 0, 0, 0);
            acc[1][nt] = __builtin_amdgcn_mfma_f32_16x16x32_bf16(a1, bfr, acc[1][nt], 0, 0, 0);
        }
    }

    #pragma unroll
    for (int mt = 0; mt < 2; ++mt) {
        int rloc = rowbase + mt * 16 + quad * 4;
        #pragma unroll
        for (int nt = 0; nt < 8; ++nt) {
            int col = nt * 16 + l16;
            #pragma unroll
            for (int r = 0; r < 4; ++r) {
                int grow = row0 + rloc + r;
                if (grow < M)
                    y[(size_t)grow * 128 + col] = f2b(acc[mt][nt][r]);
            }
        }
    }
}

// ---------------- sort: vectorized ei read -> LDS rank -> reserve -> place ------------
// 8 contiguous edges per thread (uint4 loads). Rank kept in registers between passes;
// exactly one global atomicAdd per (block,bucket). bpos[k] ends as the bucket total.
__global__ __launch_bounds__(1024) void k_sort(const int* __restrict__ ei,
                                               const int* __restrict__ flag,
                                               unsigned* __restrict__ bpos,
                                               unsigned* __restrict__ pairs) {
    __shared__ unsigned hist[KB];
    int b = blockIdx.x;
    int t = threadIdx.x;
    for (int i = t; i < KB; i += 1024) hist[i] = 0u;
    __syncthreads();
    int wide = *flag;
    int e0 = b * SCH + t * 8;
    int dv[8], sv[8], rv[8];
    if (e0 < N_EDGES) {            // full 8 edges (E - 195*8192 = 2560 = 320*8)
        if (wide) {
            const uint4* pd = (const uint4*)&ei[((size_t)N_EDGES + e0) * 2];
            const uint4* ps = (const uint4*)&ei[(size_t)e0 * 2];
            #pragma unroll
            for (int j = 0; j < 4; ++j) {
                uint4 qd = pd[j], qs = ps[j];
                dv[2 * j] = (int)qd.x; dv[2 * j + 1] = (int)qd.z;
                sv[2 * j] = (int)qs.x; sv[2 * j + 1] = (int)qs.z;
            }
        } else {
            const uint4* pd = (const uint4*)&ei[(size_t)N_EDGES + e0];
            const uint4* ps = (const uint4*)&ei[e0];
            #pragma unroll
            for (int j = 0; j < 2; ++j) {
                uint4 qd = pd[j], qs = ps[j];
                dv[4 * j] = (int)qd.x; dv[4 * j + 1] = (int)qd.y;
                dv[4 * j + 2] = (int)qd.z; dv[4 * j + 3] = (int)qd.w;
                sv[4 * j] = (int)qs.x; sv[4 * j + 1] = (int)qs.y;
                sv[4 * j + 2] = (int)qs.z; sv[4 * j + 3] = (int)qs.w;
            }
        }
    } else {
        #pragma unroll
        for (int i = 0; i < 8; ++i) dv[i] = -1;
    }
    #pragma unroll
    for (int i = 0; i < 8; ++i) {
        if ((unsigned)dv[i] < (unsigned)N_NODES) {
            rv[i] = (int)atomicAdd(&hist[dv[i] >> BSH], 1u);
            if ((unsigned)sv[i] >= (unsigned)N_NODES) sv[i] = 0;
        } else dv[i] = -1;
    }
    __syncthreads();
    for (int i = t; i < KB; i += 1024) {
        unsigned c = hist[i];
        hist[i] = c ? atomicAdd(&bpos[i], c) : 0u;   // hist now holds the global base
    }
    __syncthreads();
    #pragma unroll
    for (int i = 0; i < 8; ++i) {
        if (dv[i] >= 0) {
            int kb = dv[i] >> BSH;
            unsigned r = hist[kb] + (unsigned)rv[i];
            if (r < CAPB)
                pairs[(size_t)kb * CAPB + r] =
                    (unsigned)sv[i] | ((unsigned)(dv[i] & (BSZ - 1)) << 17);
        }
    }
}

// ---------------- bucket gather + fused layer-2 GEMM ----------------------------------
// One block (8 waves) per bucket of 64 dst nodes. Fine-sorts pairs into LDS, gathers
// with register sums into an LDS h tile (bf16, (1+eps)*self + b1 + relu applied),
// then 128 MFMAs: out[64,128] = htile @ W2^T + b2 (B-fragments from L2-hot global).
__global__ __launch_bounds__(512) void k_bgather(const unsigned short* __restrict__ y,
                                                 const unsigned* __restrict__ pairs,
                                                 const unsigned* __restrict__ bpos,
                                                 const float* __restrict__ b1,
                                                 const unsigned short* __restrict__ Wt2g,
                                                 const float* __restrict__ b2,
                                                 float* __restrict__ out) {
    __shared__ unsigned sbuf[CAPB];          // 10,240 B
    __shared__ short htile[BSZ * HP];        // 17,408 B
    __shared__ int cnt[BSZ], loff[BSZ], pos[BSZ];
    int k = blockIdx.x;
    int t = threadIdx.x;
    if (t < BSZ) cnt[t] = 0;
    __syncthreads();
    int beg = k * CAPB;
    int tot = (int)bpos[k];
    if (tot > CAPB) tot = CAPB;
    for (int i = t; i < tot; i += 512)
        atomicAdd(&cnt[pairs[beg + i] >> 17], 1);
    __syncthreads();
    if (t < BSZ) {   // wave 0: exclusive scan of the 64 counters
        int v = cnt[t];
        int xs = v;
        #pragma unroll
        for (int off = 1; off < 64; off <<= 1) {
            int u0 = __shfl_up(xs, off, 64);
            if (t >= off) xs += u0;
        }
        loff[t] = xs - v;
        pos[t] = xs - v;
    }
    __syncthreads();
    for (int i = t; i < tot; i += 512) {
        unsigned p = pairs[beg + i];
        int r = atomicAdd(&pos[p >> 17], 1);
        sbuf[r] = p & 0x1FFFFu;
    }
    __syncthreads();

    int w = t >> 6;
    int lane = t & 63;
    int g = lane >> 5;    // neighbor group 0..1
    int u = lane & 31;    // uint2 index within row (32 x 8 B = 256 B)
    const uint2* yr = (const uint2*)y;

    #pragma unroll 1
    for (int q = 0; q < 8; ++q) {     // each wave: 8 nodes
        int dl = w * 8 + q;
        int node = (k << BSH) + dl;
        int jb = loff[dl];
        int je = jb + cnt[dl];        // empty when node >= N_NODES (no such dst)
        float a0 = 0.f, a1 = 0.f, a2 = 0.f, a3 = 0.f;
        int j = jb + g;
        for (; j + 14 < je; j += 16) {
            int ss[8];
            #pragma unroll
            for (int q2 = 0; q2 < 8; ++q2) ss[q2] = (int)sbuf[j + 2 * q2];
            #pragma unroll
            for (int q2 = 0; q2 < 8; ++q2) {
                uint2 A = yr[(size_t)ss[q2] * 32 + u];
                a0 += b2f_lo(A.x); a1 += b2f_hi(A.x);
                a2 += b2f_lo(A.y); a3 += b2f_hi(A.y);
            }
        }
        for (; j < je; j += 2) {
            uint2 A = yr[(size_t)sbuf[j] * 32 + u];
            a0 += b2f_lo(A.x); a1 += b2f_hi(A.x);
            a2 += b2f_lo(A.y); a3 += b2f_hi(A.y);
        }
        a0 += __shfl_xor(a0, 32, 64); a1 += __shfl_xor(a1, 32, 64);
        a2 += __shfl_xor(a2, 32, 64); a3 += __shfl_xor(a3, 32, 64);
        if (g == 0) {
            uint2 o = make_uint2(0u, 0u);
            if (node < N_NODES) {
                uint2 S = yr[(size_t)node * 32 + u];   // self row (bf16 y)
                float4 bv = ((const float4*)b1)[u];    // bias cols 4u..4u+3
                float f0 = fmaf(1.001f, b2f_lo(S.x), a0) + bv.x;
                float f1 = fmaf(1.001f, b2f_hi(S.x), a1) + bv.y;
                float f2 = fmaf(1.001f, b2f_lo(S.y), a2) + bv.z;
                float f3 = fmaf(1.001f, b2f_hi(S.y), a3) + bv.w;
                f0 = fmaxf(f0, 0.f); f1 = fmaxf(f1, 0.f);
                f2 = fmaxf(f2, 0.f); f3 = fmaxf(f3, 0.f);
                o.x = (unsigned)f2b(f0) | ((unsigned)f2b(f1) << 16);
                o.y = (unsigned)f2b(f2) | ((unsigned)f2b(f3) << 16);
            }
            *(uint2*)&htile[dl * HP + u * 4] = o;
        }
    }
    __syncthreads();

    // ---- fused layer 2: out[64,128] = htile @ W2^T + b2 ----
    int quad = lane >> 4;
    int l16 = lane & 15;
    int mt = w >> 1;      // row tile 0..3 (16 rows each)
    int nh = w & 1;       // col half 0..1 (64 cols each)
    float4v accB[4];
    #pragma unroll
    for (int nt2 = 0; nt2 < 4; ++nt2) accB[nt2] = (float4v){0.f, 0.f, 0.f, 0.f};
    #pragma unroll
    for (int kc = 0; kc < 4; ++kc) {
        int koff = kc * 32 + quad * 8;
        short8 a = *(const short8*)&htile[(mt * 16 + l16) * HP + koff];
        #pragma unroll
        for (int nt2 = 0; nt2 < 4; ++nt2) {
            int col = nh * 64 + nt2 * 16 + l16;
            short8 bfr = *(const short8*)&Wt2g[col * 128 + koff];   // L2-hot
            accB[nt2] = __builtin_amdgcn_mfma_f32_16x16x32_bf16(a, bfr, accB[nt2], 0, 0, 0);
        }
    }
    int node0 = k << BSH;
    #pragma unroll
    for (int nt2 = 0; nt2 < 4; ++nt2) {
        int col = nh * 64 + nt2 * 16 + l16;
        float bb = b2[col];
        #pragma unroll
        for (int r = 0; r < 4; ++r) {
            int grow = node0 + mt * 16 + quad * 4 + r;
            if (grow < N_NODES)
                out[(size_t)grow * 128 + col] = accB[nt2][r] + bb;
        }
    }
}

extern "C" void kernel_launch(void* const* d_in, const int* in_sizes, int n_in,
                              void* d_out, int out_size, void* d_ws, size_t ws_size,
                              hipStream_t stream) {
    const float* x  = (const float*)d_in[0];
    const int*   ei = (const int*)d_in[1];
    const float* W1 = (const float*)d_in[2];
    const float* b1 = (const float*)d_in[3];
    const float* W2 = (const float*)d_in[4];
    const float* b2 = (const float*)d_in[5];
    float* out = (float*)d_out;

    // workspace layout (bytes):
    //   [0,        12.8e6)   y bf16 (x @ W1)
    //   [12.8e6,   20.81e6)  pairs u32: 782 buckets x 2560 slots, (dl<<17)|src
    //   [21.0e6,   ...)      bpos (782 u32), Wt1, Wt2, flag
    char* ws = (char*)d_ws;
    unsigned short* y       = (unsigned short*)(ws);
    unsigned*       pairs   = (unsigned*)(ws + 12800000);
    unsigned*       bpos    = (unsigned*)(ws + 21000000);
    unsigned short* Wt1     = (unsigned short*)(ws + 21100000);
    unsigned short* Wt2     = (unsigned short*)(ws + 21200000);
    int*            flag    = (int*)    (ws + 21300000);

    int gblocks = (N_NODES + 127) / 128;  // 391

    k_prep<<<8, 1024, 0, stream>>>(W1, W2, Wt1, Wt2, bpos, ei, flag);
    k_mm<<<gblocks, 256, 0, stream>>>(x, Wt1, y, N_NODES);
    k_sort<<<SB, 1024, 0, stream>>>(ei, flag, bpos, pairs);
    k_bgather<<<KB, 512, 0, stream>>>(y, pairs, bpos, b1, Wt2, b2, out);
}